// Round 11
// baseline (4121.115 us; speedup 1.0000x reference)
//
#include <hip/hip_runtime.h>

// ---------------- problem constants ----------------
#define B_  64
#define S_  512
#define L_  16
#define WD_ 200
#define CD_ 30
#define FN_ 4
#define KW_ 3
#define H_  256
#define T_  17
#define D_  320   // WD + CD*FN
#define PITCH 280  // h-row pitch in ushorts: 140 dwords == 12 mod 32 -> conflict-free b128

typedef unsigned short ushort_t;
typedef __attribute__((ext_vector_type(8))) short v8s;   // bf16x8 MFMA frag
typedef __attribute__((ext_vector_type(4))) float v4f;   // fp32x4 MFMA acc
typedef __attribute__((ext_vector_type(4))) float f4;
typedef __attribute__((ext_vector_type(4))) unsigned int ui4;
typedef __attribute__((ext_vector_type(4))) unsigned short us4;

__device__ __forceinline__ float bf2f(unsigned short u) {
  union { unsigned int i; float f; } v; v.i = ((unsigned int)u) << 16; return v.f;
}
__device__ __forceinline__ unsigned short f2bf(float f) {
  union { float f; unsigned int i; } v; v.f = f;
  unsigned int r = v.i + 0x7fffu + ((v.i >> 16) & 1u);   // RNE
  return (unsigned short)(r >> 16);
}
// barrier that does NOT drain vmcnt (keeps global prefetch loads in flight)
__device__ __forceinline__ void block_sync_lds() {
  __asm__ volatile("s_waitcnt lgkmcnt(0)\n\ts_barrier" ::: "memory");
}

// ---------------- K0: one-time W_ih f32->bf16 conversion (into dead hs region) -----------------
__global__ __launch_bounds__(256) void k_wcvt(
    const float* __restrict__ wf, const float* __restrict__ wb,
    ushort_t* __restrict__ wbf)
{
  int idx = (blockIdx.x * 256 + threadIdx.x) * 4;   // 640 blocks: covers 2*1024*320
  const float* src = (idx < 327680) ? (wf + idx) : (wb + (idx - 327680));
  f4 v = *(const f4*)src;
  us4 o; o[0]=f2bf(v[0]); o[1]=f2bf(v[1]); o[2]=f2bf(v[2]); o[3]=f2bf(v[3]);
  *(us4*)(wbf + idx) = o;
}

// ---------------- K1: word emb (f32->bf16) + char CNN + maxpool -> z [(s,b)-major, 320] ---------
__global__ __launch_bounds__(256) void k_embed(
    const int* __restrict__ tok, const int* __restrict__ ctok,
    const float* __restrict__ wemb, const float* __restrict__ cemb,
    const float* __restrict__ cw, const float* __restrict__ cb,
    ushort_t* __restrict__ z)
{
  int g = threadIdx.x >> 6;           // word slot in block
  int l = threadIdx.x & 63;
  int w = blockIdx.x * 4 + g;         // input word index = b*S + s
  int b = w >> 9, s = w & 511;
  size_t ro = (size_t)s * 64 + b;     // OUTPUT row: (s,b)-major
  __shared__ float ce[4][L_][32];
  if (l < L_) {
    int cid = ctok[w * L_ + l];
    const float* row = cemb + (size_t)cid * CD_;
    #pragma unroll
    for (int j = 0; j < CD_; ++j) ce[g][l][j] = row[j];
  }
  int t = tok[w];
  const f4* src = (const f4*)(wemb + (size_t)t * WD_);
  if (l < 50) {
    f4 v = src[l];
    us4 o; o[0]=f2bf(v[0]); o[1]=f2bf(v[1]); o[2]=f2bf(v[2]); o[3]=f2bf(v[3]);
    *(us4*)(z + ro * D_ + l*4) = o;
  }
  __syncthreads();
  for (int oc = l; oc < CD_ * FN_; oc += 64) {
    int c = oc >> 2;
    float w0 = cw[oc*3+0], w1 = cw[oc*3+1], w2 = cw[oc*3+2];
    float mx = -3e30f;
    #pragma unroll
    for (int p = 0; p < L_ - KW_ + 1; ++p) {
      float sv = ce[g][p][c]*w0 + ce[g][p+1][c]*w1 + ce[g][p+2][c]*w2;
      mx = fmaxf(mx, sv);
    }
    z[ro * D_ + WD_ + oc] = f2bf(mx + cb[oc]);
  }
}

// ---------------- K2: gx2 = z @ W_ih^T + b, packed for k_lstm lane-slots (us4 stores) -----------
// gx2 idx = ((dir*512+s)*4+bg)*16384 + (((w2*2+j)*4+gate)*16+lm2)*16 + b_local (bf16)
__global__ __launch_bounds__(256) void k_gemm_gx(
    const ushort_t* __restrict__ z, const ushort_t* __restrict__ wbf,
    const float* __restrict__ bfv, const float* __restrict__ bbv,
    ushort_t* __restrict__ gx2)
{
  __shared__ ushort_t As[128 * 40];
  __shared__ ushort_t Bs[64 * 40];
  int m0 = blockIdx.x * 128;          // m = s*64 + b (z is (s,b)-major)
  int n0g = blockIdx.y * 64;
  int dir = n0g >> 10;
  int ncol0 = n0g & 1023;
  const ushort_t* Wb = wbf + (size_t)dir * 327680;
  const float* bias = dir ? bbv : bfv;
  int tid = threadIdx.x;
  int wv = tid >> 6, l = tid & 63;
  int lm = l & 15, lq = l >> 4;
  v4f acc[2][4];
  #pragma unroll
  for (int i = 0; i < 2; i++)
    #pragma unroll
    for (int j = 0; j < 4; j++) acc[i][j] = (v4f)0.f;

  for (int kc = 0; kc < 10; ++kc) {
    int k0 = kc * 32;
    #pragma unroll
    for (int rep = 0; rep < 2; ++rep) {
      int idx = rep * 256 + tid;
      int row = idx >> 2, q = idx & 3;
      *(ui4*)(As + row*40 + q*8) =
          *(const ui4*)(z + (size_t)(m0 + row)*D_ + k0 + q*8);
    }
    {
      int row = tid >> 2, q = tid & 3;
      *(ui4*)(Bs + row*40 + q*8) =
          *(const ui4*)(Wb + (size_t)(ncol0 + row)*D_ + k0 + q*8);
    }
    __syncthreads();
    v8s a0 = *(const v8s*)(As + (wv*32 + lm)*40 + lq*8);
    v8s a1 = *(const v8s*)(As + (wv*32 + 16 + lm)*40 + lq*8);
    #pragma unroll
    for (int nt = 0; nt < 4; ++nt) {
      v8s b = *(const v8s*)(Bs + (nt*16 + lm)*40 + lq*8);
      acc[0][nt] = __builtin_amdgcn_mfma_f32_16x16x32_bf16(a0, b, acc[0][nt], 0, 0, 0);
      acc[1][nt] = __builtin_amdgcn_mfma_f32_16x16x32_bf16(a1, b, acc[1][nt], 0, 0, 0);
    }
    __syncthreads();
  }
  // epilogue: r spans 4 consecutive batches -> one aligned us4 store each
  float bval[4];
  #pragma unroll
  for (int nt = 0; nt < 4; nt++) bval[nt] = bias[ncol0 + nt*16 + lm];
  #pragma unroll
  for (int mt = 0; mt < 2; mt++)
    #pragma unroll
    for (int nt = 0; nt < 4; nt++) {
      int m = m0 + wv*32 + mt*16 + lq*4;   // + r
      int b = m & 63, s = m >> 6;
      int col = ncol0 + nt*16 + lm;
      int gate = col >> 8, unit = col & 255;
      int w2 = unit >> 5, j = (unit >> 4) & 1, lm2 = unit & 15;
      int bg = b >> 4, bl = b & 15;        // bl multiple of 4
      us4 o;
      #pragma unroll
      for (int r = 0; r < 4; r++) o[r] = f2bf(acc[mt][nt][r] + bval[nt]);
      size_t idx = ((size_t)(dir*512 + s)*4 + bg)*16384
                 + (size_t)(((w2*2 + j)*4 + gate)*16 + lm2)*16 + bl;
      *(us4*)(gx2 + idx) = o;
    }
}

// ---------------- K3: intra-CU persistent LSTM v11 ----------------------------------------------
// v10 (static double-buffer hshA/hshB, proven -20%) + ALL W_hh in registers:
//  - wfr extended to [8][8] (ti 6,7 = gates g,o upper 16): exactly 256 AGPRs; the 128 KB Wl
//    LDS buffer and its 16 b128 reads/wave/step are GONE (MFMA reads B straight from AGPR,
//    already proven at 192 AGPRs in v6-v10).
//  - passA stashes its A-fragments in Areg[8] (+32 VGPR, static indexing); passB is a pure
//    register MFMA burst -- its 8 A re-reads are gone.
// LDS traffic/wave/step: 33 -> 9 b128-equiv. Budget at 2 waves/SIMD is ~512 unified regs/wave;
// we use ~160 VGPR + 256 AGPR. Two-pass + epilogue phase structure preserved (v8/v9 lesson).
#define LSTM_STEP(NN, HRD_ARR, HWR_ARR)                                                   \
  {                                                                                       \
    int n = (NN);                                                                         \
    int t = dir ? (511 - n) : n;                                                          \
    const ushort_t* hrd = &HRD_ARR[0][0];                                                 \
    ushort_t* hwr = &HWR_ARR[0][0];                                                       \
    if (n > 0) {                                                                          \
      int tp = dir ? (512 - n) : (n - 1);                                                 \
      ui4 hv = *(const ui4*)(hrd + db*PITCH + du);                                        \
      *(ui4*)(hs + ((size_t)(dir*512 + tp)*64 + bg*16 + db)*256 + du) = hv;               \
    }                                                                                     \
    const ushort_t* gnext = gx2                                                           \
        + ((size_t)(dir*512 + (dir ? (511 - ((n < 511) ? n+1 : n))                        \
                                   : ((n < 511) ? n+1 : n)))*4 + bg)*16384;               \
    v4f a0, a1, a2, a3;                                                                   \
    _Pragma("unroll")                                                                     \
    for (int r = 0; r < 4; r++) {                                                         \
      a0[r] = bf2f(gA[0][r]); a1[r] = bf2f(gA[1][r]);                                     \
      a2[r] = bf2f(gA[2][r]); a3[r] = bf2f(gA[3][r]);                                     \
    }                                                                                     \
    v8s Areg[8];                                                                          \
    {                                                                                     \
      v8s A = *(const v8s*)(hrd + lm*PITCH + lq*8);                                       \
      __builtin_amdgcn_s_setprio(1);                                                      \
      _Pragma("unroll")                                                                   \
      for (int kc = 0; kc < 8; kc++) {                                                    \
        v8s An = (kc < 7) ? *(const v8s*)(hrd + lm*PITCH + (kc+1)*32 + lq*8) : A;         \
        Areg[kc] = A;                                                                     \
        a0 = __builtin_amdgcn_mfma_f32_16x16x32_bf16(A, wfr[0][kc], a0, 0, 0, 0);         \
        a1 = __builtin_amdgcn_mfma_f32_16x16x32_bf16(A, wfr[1][kc], a1, 0, 0, 0);         \
        a2 = __builtin_amdgcn_mfma_f32_16x16x32_bf16(A, wfr[2][kc], a2, 0, 0, 0);         \
        a3 = __builtin_amdgcn_mfma_f32_16x16x32_bf16(A, wfr[3][kc], a3, 0, 0, 0);         \
        A = An;                                                                           \
      }                                                                                   \
      __builtin_amdgcn_s_setprio(0);                                                      \
    }                                                                                     \
    {                                                                                     \
      float hv0, hv1, hv2, hv3;                                                           \
      _Pragma("unroll")                                                                   \
      for (int r = 0; r < 4; r++) {                                                       \
        float ei = __expf(-a0[r]), ef = __expf(-a1[r]);                                   \
        float eg = __expf(2.f*a2[r]), eo = __expf(-a3[r]);                                \
        float p1 = (1.f + ei) * (eg + 1.f);                                               \
        float p2 = 1.f + ef;                                                              \
        float R  = __builtin_amdgcn_rcpf(p1 * p2);                                        \
        float ig = (eg - 1.f) * p2 * R;                                                   \
        float fa = p1 * R;                                                                \
        c0[r] = fa*c0[r] + ig;                                                            \
        float ec = __expf(2.f*c0[r]);                                                     \
        float hv = (ec - 1.f) * __builtin_amdgcn_rcpf((1.f + eo)*(ec + 1.f));             \
        if (r == 0) hv0 = hv; else if (r == 1) hv1 = hv;                                  \
        else if (r == 2) hv2 = hv; else hv3 = hv;                                         \
      }                                                                                   \
      unsigned int pk01, pk23;                                                            \
      asm("v_cvt_pk_bf16_f32 %0, %1, %2" : "=v"(pk01) : "v"(hv0), "v"(hv1));              \
      asm("v_cvt_pk_bf16_f32 %0, %1, %2" : "=v"(pk23) : "v"(hv2), "v"(hv3));              \
      hwr[(lq*4 + 0)*PITCH + u0] = (ushort_t)pk01;                                        \
      hwr[(lq*4 + 1)*PITCH + u0] = (ushort_t)(pk01 >> 16);                                \
      hwr[(lq*4 + 2)*PITCH + u0] = (ushort_t)pk23;                                        \
      hwr[(lq*4 + 3)*PITCH + u0] = (ushort_t)(pk23 >> 16);                                \
    }                                                                                     \
    _Pragma("unroll")                                                                     \
    for (int k = 0; k < 4; k++) gA[k] = *(const us4*)(gnext + goff[k]);                   \
    v4f a4, a5, a6, a7;                                                                   \
    _Pragma("unroll")                                                                     \
    for (int r = 0; r < 4; r++) {                                                         \
      a4[r] = bf2f(gB[0][r]); a5[r] = bf2f(gB[1][r]);                                     \
      a6[r] = bf2f(gB[2][r]); a7[r] = bf2f(gB[3][r]);                                     \
    }                                                                                     \
    {                                                                                     \
      __builtin_amdgcn_s_setprio(1);                                                      \
      _Pragma("unroll")                                                                   \
      for (int kc = 0; kc < 8; kc++) {                                                    \
        a4 = __builtin_amdgcn_mfma_f32_16x16x32_bf16(Areg[kc], wfr[4][kc], a4, 0, 0, 0);  \
        a5 = __builtin_amdgcn_mfma_f32_16x16x32_bf16(Areg[kc], wfr[5][kc], a5, 0, 0, 0);  \
        a6 = __builtin_amdgcn_mfma_f32_16x16x32_bf16(Areg[kc], wfr[6][kc], a6, 0, 0, 0);  \
        a7 = __builtin_amdgcn_mfma_f32_16x16x32_bf16(Areg[kc], wfr[7][kc], a7, 0, 0, 0);  \
      }                                                                                   \
      __builtin_amdgcn_s_setprio(0);                                                      \
    }                                                                                     \
    {                                                                                     \
      float hv0, hv1, hv2, hv3;                                                           \
      _Pragma("unroll")                                                                   \
      for (int r = 0; r < 4; r++) {                                                       \
        float ei = __expf(-a4[r]), ef = __expf(-a5[r]);                                   \
        float eg = __expf(2.f*a6[r]), eo = __expf(-a7[r]);                                \
        float p1 = (1.f + ei) * (eg + 1.f);                                               \
        float p2 = 1.f + ef;                                                              \
        float R  = __builtin_amdgcn_rcpf(p1 * p2);                                        \
        float ig = (eg - 1.f) * p2 * R;                                                   \
        float fa = p1 * R;                                                                \
        c1[r] = fa*c1[r] + ig;                                                            \
        float ec = __expf(2.f*c1[r]);                                                     \
        float hv = (ec - 1.f) * __builtin_amdgcn_rcpf((1.f + eo)*(ec + 1.f));             \
        if (r == 0) hv0 = hv; else if (r == 1) hv1 = hv;                                  \
        else if (r == 2) hv2 = hv; else hv3 = hv;                                         \
      }                                                                                   \
      unsigned int pk01, pk23;                                                            \
      asm("v_cvt_pk_bf16_f32 %0, %1, %2" : "=v"(pk01) : "v"(hv0), "v"(hv1));              \
      asm("v_cvt_pk_bf16_f32 %0, %1, %2" : "=v"(pk23) : "v"(hv2), "v"(hv3));              \
      hwr[(lq*4 + 0)*PITCH + u1] = (ushort_t)pk01;                                        \
      hwr[(lq*4 + 1)*PITCH + u1] = (ushort_t)(pk01 >> 16);                                \
      hwr[(lq*4 + 2)*PITCH + u1] = (ushort_t)pk23;                                        \
      hwr[(lq*4 + 3)*PITCH + u1] = (ushort_t)(pk23 >> 16);                                \
    }                                                                                     \
    _Pragma("unroll")                                                                     \
    for (int k = 0; k < 4; k++) gB[k] = *(const us4*)(gnext + goff[4 + k]);               \
    block_sync_lds();                                                                     \
  }

__global__ __launch_bounds__(512, 2) void k_lstm(
    const ushort_t* __restrict__ gx2,
    const float* __restrict__ whhf, const float* __restrict__ whhb,
    ushort_t* __restrict__ hs)
{
  __shared__ ushort_t hshA[16][PITCH];        // read at even n, written at odd n
  __shared__ ushort_t hshB[16][PITCH];        // read at odd n, written at even n
  int bid = blockIdx.x;
  int dir = bid >> 2, bg = bid & 3;
  int tid = threadIdx.x, w = tid >> 6, l = tid & 63;
  int lm = l & 15, lq = l >> 4;
  const float* W = dir ? whhb : whhf;

  for (int i = tid; i < 16 * PITCH; i += 512) {
    (&hshA[0][0])[i] = 0;
    (&hshB[0][0])[i] = 0;
  }
  // register W tiles, ALL of W_hh for this wave's 32 units x 4 gates (256 AGPRs):
  // ti 0..3 = gates i,f,g,o (lower 16 units); ti 4..7 = gates i,f,g,o (upper 16 units)
  v8s wfr[8][8];
  #pragma unroll
  for (int ti = 0; ti < 8; ti++) {
    int gate = (ti < 4) ? ti : (ti - 4);
    int jr = (ti < 4) ? 0 : 16;
    #pragma unroll
    for (int kc = 0; kc < 8; kc++) {
      const float* src = W + (size_t)(gate*256 + w*32 + jr + lm)*256 + kc*32 + lq*8;
      v8s f;
      #pragma unroll
      for (int jj = 0; jj < 8; jj++) f[jj] = (short)f2bf(src[jj]);
      wfr[ti][kc] = f;
    }
  }
  __syncthreads();

  float c0[4] = {0.f,0.f,0.f,0.f}, c1[4] = {0.f,0.f,0.f,0.f};
  int u0 = w*32 + lm, u1 = w*32 + 16 + lm;
  int goff[8];
  #pragma unroll
  for (int j = 0; j < 2; j++)
    #pragma unroll
    for (int ga = 0; ga < 4; ga++)
      goff[j*4 + ga] = (((w*2 + j)*4 + ga)*16 + lm)*16 + lq*4;
  // hs-dump lane mapping: one 16B slot per lane covers hsh[16][256]
  int db = tid >> 5, du = (tid & 31) * 8;

  us4 gA[4], gB[4];
  {
    int t0 = dir ? 511 : 0;
    const ushort_t* gb = gx2 + ((size_t)(dir*512 + t0)*4 + bg)*16384;
    #pragma unroll
    for (int k = 0; k < 4; k++) gA[k] = *(const us4*)(gb + goff[k]);
    #pragma unroll
    for (int k = 0; k < 4; k++) gB[k] = *(const us4*)(gb + goff[4 + k]);
  }

  for (int n2 = 0; n2 < 512; n2 += 2) {
    LSTM_STEP(n2,     hshA, hshB);   // read A (parity 0), write B
    LSTM_STEP(n2 + 1, hshB, hshA);   // read B (parity 1), write A
  }
  // final h dump: h at t_last was written by body n=511 into hshA (parity 0)
  {
    int tp = dir ? 0 : 511;
    const ushort_t* hfin = &hshA[0][0];
    ui4 hv = *(const ui4*)(hfin + db*PITCH + du);
    *(ui4*)(hs + ((size_t)(dir*512 + tp)*64 + bg*16 + db)*256 + du) = hv;
  }
}

// ---------------- K4: emissions[b][s][17] = [h_f, h_b] @ cls_w^T + cls_b (fp32) ----------------
__global__ __launch_bounds__(256) void k_emis(
    const ushort_t* __restrict__ hs, const float* __restrict__ clsw,
    const float* __restrict__ clsb, float* __restrict__ emis)
{
  int tid = threadIdx.x;
  if (tid >= 255) return;
  int wi = blockIdx.x * 15 + tid / 17;
  int tau = tid % 17;
  if (wi >= B_ * S_) return;
  int b = wi >> 9, s = wi & 511;
  const ushort_t* hf  = hs + ((size_t)s*64 + b) * 256;
  const ushort_t* hbk = hs + (((size_t)512 + s)*64 + b) * 256;
  const float* cwf = clsw + (size_t)tau * 512;
  const float* cwb = cwf + 256;
  union { unsigned int u; float f; } bc;
  float acc = clsb[tau];
  #pragma unroll 4
  for (int k = 0; k < 256; k += 8) {
    ui4 h8 = *(const ui4*)(hf + k);
    f4 wa = *(const f4*)(cwf + k); f4 wb = *(const f4*)(cwf + k + 4);
    bc.u = h8[0] << 16;           acc += bc.f * wa[0];
    bc.u = h8[0] & 0xffff0000u;   acc += bc.f * wa[1];
    bc.u = h8[1] << 16;           acc += bc.f * wa[2];
    bc.u = h8[1] & 0xffff0000u;   acc += bc.f * wa[3];
    bc.u = h8[2] << 16;           acc += bc.f * wb[0];
    bc.u = h8[2] & 0xffff0000u;   acc += bc.f * wb[1];
    bc.u = h8[3] << 16;           acc += bc.f * wb[2];
    bc.u = h8[3] & 0xffff0000u;   acc += bc.f * wb[3];
  }
  #pragma unroll 4
  for (int k = 0; k < 256; k += 8) {
    ui4 h8 = *(const ui4*)(hbk + k);
    f4 wa = *(const f4*)(cwb + k); f4 wb = *(const f4*)(cwb + k + 4);
    bc.u = h8[0] << 16;           acc += bc.f * wa[0];
    bc.u = h8[0] & 0xffff0000u;   acc += bc.f * wa[1];
    bc.u = h8[1] << 16;           acc += bc.f * wa[2];
    bc.u = h8[1] & 0xffff0000u;   acc += bc.f * wa[3];
    bc.u = h8[2] << 16;           acc += bc.f * wb[0];
    bc.u = h8[2] & 0xffff0000u;   acc += bc.f * wb[1];
    bc.u = h8[3] << 16;           acc += bc.f * wb[2];
    bc.u = h8[3] & 0xffff0000u;   acc += bc.f * wb[3];
  }
  emis[(size_t)wi * 17 + tau] = acc;
}

// ---------------- K5: CRF — 64 blocks (one per batch): wave0 = loss fwd, wave1 = viterbi --------
__global__ __launch_bounds__(128) void k_crf(
    const float* __restrict__ emis, const int* __restrict__ labels,
    const int* __restrict__ mask, const float* __restrict__ startt,
    const float* __restrict__ endt, const float* __restrict__ trans,
    float* __restrict__ lossp, float* __restrict__ outp)
{
  __shared__ unsigned char bps[511][17];
  int b = blockIdx.x;
  int tid = threadIdx.x, wv = tid >> 6, l = tid & 63;
  int tauc = (l < 17) ? l : 0;
  float tc[17];
  #pragma unroll
  for (int i = 0; i < 17; i++) tc[i] = trans[i*17 + tauc];
  const float* eb = emis + (size_t)b * 512 * 17;
  float alpha = startt[tauc] + eb[tauc];
  if (l >= 17) alpha = -3e30f;

  if (wv == 0) {
    float e_cur = (l < 17) ? eb[17 + l] : 0.f;
    int   m_cur = mask[b*512 + 1];
    for (int t = 1; t < 512; t++) {
      float e_nxt = 0.f; int m_nxt = 1;
      if (t < 511) {
        e_nxt = (l < 17) ? eb[(t+1)*17 + l] : 0.f;
        m_nxt = mask[b*512 + t + 1];
      }
      float arr[17];
      #pragma unroll
      for (int i = 0; i < 17; i++) arr[i] = __shfl(alpha, i) + tc[i];
      // depth-5 fmax tree
      float t8[8];
      #pragma unroll
      for (int i = 0; i < 8; i++) t8[i] = fmaxf(arr[2*i], arr[2*i+1]);
      float t4a = fmaxf(t8[0], t8[1]), t4b = fmaxf(t8[2], t8[3]);
      float t4c = fmaxf(t8[4], t8[5]), t4d = fmaxf(t8[6], t8[7]);
      float mx = fmaxf(fmaxf(fmaxf(t4a, t4b), fmaxf(t4c, t4d)), arr[16]);
      // exp + depth-5 add tree
      float ex[17];
      #pragma unroll
      for (int i = 0; i < 17; i++) ex[i] = __expf(arr[i] - mx);
      float s8[8];
      #pragma unroll
      for (int i = 0; i < 8; i++) s8[i] = ex[2*i] + ex[2*i+1];
      float ss = (((s8[0] + s8[1]) + (s8[2] + s8[3]))
               + ((s8[4] + s8[5]) + (s8[6] + s8[7]))) + ex[16];
      float nxt = mx + __logf(ss) + e_cur;
      if (m_cur > 0 && l < 17) alpha = nxt;
      e_cur = e_nxt; m_cur = m_nxt;
    }
    float a2 = (l < 17) ? (alpha + endt[l]) : -3e30f;
    float mx = a2;
    #pragma unroll
    for (int o = 32; o > 0; o >>= 1) mx = fmaxf(mx, __shfl_xor(mx, o));
    float ss = (l < 17) ? __expf(a2 - mx) : 0.f;
    #pragma unroll
    for (int o = 32; o > 0; o >>= 1) ss += __shfl_xor(ss, o);
    float denom = mx + __logf(ss);
    float ns = 0.f; int msum = 0;
    for (int t = l; t < 512; t += 64) {
      int tg = labels[b*512 + t];
      int mt = mask[b*512 + t];
      msum += (mt > 0);
      if (mt > 0) {
        ns += eb[t*17 + tg];
        if (t > 0) ns += trans[labels[b*512 + t - 1]*17 + tg];
      }
    }
    #pragma unroll
    for (int o = 32; o > 0; o >>= 1) { ns += __shfl_xor(ns, o); msum += __shfl_xor(msum, o); }
    if (l == 0) {
      int lidx = msum - 1;
      float num = ns + startt[labels[b*512]] + endt[labels[b*512 + lidx]];
      lossp[b] = num - denom;
    }
  } else {
    float e_cur = (l < 17) ? eb[17 + l] : 0.f;
    int   m_cur = mask[b*512 + 1];
    for (int t = 1; t < 512; t++) {
      float e_nxt = 0.f; int m_nxt = 1;
      if (t < 511) {
        e_nxt = (l < 17) ? eb[(t+1)*17 + l] : 0.f;
        m_nxt = mask[b*512 + t + 1];
      }
      float av[17];
      #pragma unroll
      for (int i = 0; i < 17; i++) av[i] = __shfl(alpha, i) + tc[i];
      // depth-5 argmax tournament, left-priority (>=): first-max == np.argmax
      float v8l[8]; int i8[8];
      #pragma unroll
      for (int i = 0; i < 8; i++) {
        int take = (av[2*i] >= av[2*i+1]);
        v8l[i] = take ? av[2*i] : av[2*i+1];
        i8[i]  = take ? 2*i : 2*i+1;
      }
      float v4l[4]; int i4[4];
      #pragma unroll
      for (int i = 0; i < 4; i++) {
        int take = (v8l[2*i] >= v8l[2*i+1]);
        v4l[i] = take ? v8l[2*i] : v8l[2*i+1];
        i4[i]  = take ? i8[2*i] : i8[2*i+1];
      }
      float v2a = (v4l[0] >= v4l[1]) ? v4l[0] : v4l[1];
      int   i2a = (v4l[0] >= v4l[1]) ? i4[0] : i4[1];
      float v2b = (v4l[2] >= v4l[3]) ? v4l[2] : v4l[3];
      int   i2b = (v4l[2] >= v4l[3]) ? i4[2] : i4[3];
      float v1 = (v2a >= v2b) ? v2a : v2b;
      int   i1 = (v2a >= v2b) ? i2a : i2b;
      float best = (v1 >= av[16]) ? v1 : av[16];
      int   bi   = (v1 >= av[16]) ? i1 : 16;
      float nxt = best + e_cur;
      int bpv = (m_cur > 0) ? bi : l;
      if (l < 17) {
        bps[t-1][l] = (unsigned char)bpv;
        if (m_cur > 0) alpha = nxt;
      }
      e_cur = e_nxt; m_cur = m_nxt;
    }
    float a2 = (l < 17) ? (alpha + endt[l]) : -3e30f;
    float av[17];
    #pragma unroll
    for (int i = 0; i < 17; i++) av[i] = __shfl(a2, i);
    int bt = 0; float bv2 = av[0];
    #pragma unroll
    for (int i = 1; i < 17; i++) if (av[i] > bv2) { bv2 = av[i]; bt = i; }
    if (l == 0) outp[1 + b*512 + 511] = (float)bt;
    int tg = bt;
    for (int t = 510; t >= 0; --t) {
      tg = bps[t][tg];
      if (l == 0) outp[1 + b*512 + t] = (float)tg;
    }
  }
}

// ---------------- K6: loss = -mean(num - denom), fp32 ----------------
__global__ __launch_bounds__(64) void k_final(const float* __restrict__ lossp,
                                              float* __restrict__ outp)
{
  int l = threadIdx.x;
  float v = lossp[l];
  #pragma unroll
  for (int o = 32; o > 0; o >>= 1) v += __shfl_xor(v, o);
  if (l == 0) outp[0] = -(v / 64.f);
}

// ---------------- host ----------------
extern "C" void kernel_launch(void* const* d_in, const int* in_sizes, int n_in,
                              void* d_out, int out_size, void* d_ws, size_t ws_size,
                              hipStream_t stream)
{
  (void)in_sizes; (void)n_in; (void)out_size; (void)ws_size;
  const int*   tok   = (const int*)d_in[0];
  const int*   ctok  = (const int*)d_in[1];
  const int*   labels= (const int*)d_in[2];
  const int*   amask = (const int*)d_in[3];
  const float* wemb  = (const float*)d_in[4];
  const float* cemb  = (const float*)d_in[5];
  const float* convw = (const float*)d_in[6];
  const float* convb = (const float*)d_in[7];
  const float* wihf  = (const float*)d_in[8];
  const float* whhf  = (const float*)d_in[9];
  const float* bfv   = (const float*)d_in[10];
  const float* wihb  = (const float*)d_in[11];
  const float* whhb  = (const float*)d_in[12];
  const float* bbv   = (const float*)d_in[13];
  const float* clsw  = (const float*)d_in[14];
  const float* clsb  = (const float*)d_in[15];
  const float* stt   = (const float*)d_in[16];
  const float* ent   = (const float*)d_in[17];
  const float* trn   = (const float*)d_in[18];

  // workspace layout (bytes): [z 20,971,520][gx2 134,217,728][hs 33,554,432]
  //                           [emis 2,228,224][lossp 256]
  // W_ih bf16 (1.3 MB) aliases the START of the hs region: written by k_wcvt and read by
  // k_gemm_gx, both of which complete (stream-ordered) before k_lstm writes hs.
  char* ws = (char*)d_ws;
  ushort_t* z    = (ushort_t*)(ws);
  ushort_t* gx2  = (ushort_t*)(ws + 20971520);
  ushort_t* hs   = (ushort_t*)(ws + 155189248);
  float*    emis = (float*)(ws + 188743680);
  float*    lossp= (float*)(ws + 190971904);
  ushort_t* wbf  = (ushort_t*)(ws + 155189248);   // aliases hs (dead until k_lstm)

  hipLaunchKernelGGL(k_wcvt,    dim3(640),         dim3(256), 0, stream,
                     wihf, wihb, wbf);
  hipLaunchKernelGGL(k_embed,   dim3(B_*S_/4),     dim3(256), 0, stream,
                     tok, ctok, wemb, cemb, convw, convb, z);
  hipLaunchKernelGGL(k_gemm_gx, dim3(256, 32),     dim3(256), 0, stream,
                     z, wbf, bfv, bbv, gx2);
  hipLaunchKernelGGL(k_lstm,    dim3(8),           dim3(512), 0, stream,
                     gx2, whhf, whhb, hs);
  hipLaunchKernelGGL(k_emis,    dim3((B_*S_ + 14)/15), dim3(256), 0, stream,
                     hs, clsw, clsb, emis);
  hipLaunchKernelGGL(k_crf,     dim3(64),          dim3(128), 0, stream,
                     emis, labels, amask, stt, ent, trn, lossp, (float*)d_out);
  hipLaunchKernelGGL(k_final,   dim3(1),           dim3(64),  0, stream,
                     lossp, (float*)d_out);
}

// Round 12
// 2533.236 us; speedup vs baseline: 1.6268x; 1.6268x over previous
//
#include <hip/hip_runtime.h>

// ---------------- problem constants ----------------
#define B_  64
#define S_  512
#define L_  16
#define WD_ 200
#define CD_ 30
#define FN_ 4
#define KW_ 3
#define H_  256
#define T_  17
#define D_  320   // WD + CD*FN
#define PITCH 280  // h-row pitch in ushorts: 140 dwords == 12 mod 32 -> conflict-free b128

typedef unsigned short ushort_t;
typedef __attribute__((ext_vector_type(8))) short v8s;   // bf16x8 MFMA frag
typedef __attribute__((ext_vector_type(4))) float v4f;   // fp32x4 MFMA acc
typedef __attribute__((ext_vector_type(4))) float f4;
typedef __attribute__((ext_vector_type(4))) unsigned int ui4;
typedef __attribute__((ext_vector_type(4))) unsigned short us4;

__device__ __forceinline__ float bf2f(unsigned short u) {
  union { unsigned int i; float f; } v; v.i = ((unsigned int)u) << 16; return v.f;
}
__device__ __forceinline__ unsigned short f2bf(float f) {
  union { float f; unsigned int i; } v; v.f = f;
  unsigned int r = v.i + 0x7fffu + ((v.i >> 16) & 1u);   // RNE
  return (unsigned short)(r >> 16);
}
// barrier that does NOT drain vmcnt (keeps global prefetch loads in flight)
__device__ __forceinline__ void block_sync_lds() {
  __asm__ volatile("s_waitcnt lgkmcnt(0)\n\ts_barrier" ::: "memory");
}

// ---------------- K0: one-time W_ih f32->bf16 conversion (into dead hs region) -----------------
__global__ __launch_bounds__(256) void k_wcvt(
    const float* __restrict__ wf, const float* __restrict__ wb,
    ushort_t* __restrict__ wbf)
{
  int idx = (blockIdx.x * 256 + threadIdx.x) * 4;   // 640 blocks: covers 2*1024*320
  const float* src = (idx < 327680) ? (wf + idx) : (wb + (idx - 327680));
  f4 v = *(const f4*)src;
  us4 o; o[0]=f2bf(v[0]); o[1]=f2bf(v[1]); o[2]=f2bf(v[2]); o[3]=f2bf(v[3]);
  *(us4*)(wbf + idx) = o;
}

// ---------------- K1: word emb (f32->bf16) + char CNN + maxpool -> z [(s,b)-major, 320] ---------
__global__ __launch_bounds__(256) void k_embed(
    const int* __restrict__ tok, const int* __restrict__ ctok,
    const float* __restrict__ wemb, const float* __restrict__ cemb,
    const float* __restrict__ cw, const float* __restrict__ cb,
    ushort_t* __restrict__ z)
{
  int g = threadIdx.x >> 6;           // word slot in block
  int l = threadIdx.x & 63;
  int w = blockIdx.x * 4 + g;         // input word index = b*S + s
  int b = w >> 9, s = w & 511;
  size_t ro = (size_t)s * 64 + b;     // OUTPUT row: (s,b)-major
  __shared__ float ce[4][L_][32];
  if (l < L_) {
    int cid = ctok[w * L_ + l];
    const float* row = cemb + (size_t)cid * CD_;
    #pragma unroll
    for (int j = 0; j < CD_; ++j) ce[g][l][j] = row[j];
  }
  int t = tok[w];
  const f4* src = (const f4*)(wemb + (size_t)t * WD_);
  if (l < 50) {
    f4 v = src[l];
    us4 o; o[0]=f2bf(v[0]); o[1]=f2bf(v[1]); o[2]=f2bf(v[2]); o[3]=f2bf(v[3]);
    *(us4*)(z + ro * D_ + l*4) = o;
  }
  __syncthreads();
  for (int oc = l; oc < CD_ * FN_; oc += 64) {
    int c = oc >> 2;
    float w0 = cw[oc*3+0], w1 = cw[oc*3+1], w2 = cw[oc*3+2];
    float mx = -3e30f;
    #pragma unroll
    for (int p = 0; p < L_ - KW_ + 1; ++p) {
      float sv = ce[g][p][c]*w0 + ce[g][p+1][c]*w1 + ce[g][p+2][c]*w2;
      mx = fmaxf(mx, sv);
    }
    z[ro * D_ + WD_ + oc] = f2bf(mx + cb[oc]);
  }
}

// ---------------- K2: gx2 = z @ W_ih^T + b, packed for k_lstm lane-slots (us4 stores) -----------
// gx2 idx = ((dir*512+s)*4+bg)*16384 + (((w2*2+j)*4+gate)*16+lm2)*16 + b_local (bf16)
__global__ __launch_bounds__(256) void k_gemm_gx(
    const ushort_t* __restrict__ z, const ushort_t* __restrict__ wbf,
    const float* __restrict__ bfv, const float* __restrict__ bbv,
    ushort_t* __restrict__ gx2)
{
  __shared__ ushort_t As[128 * 40];
  __shared__ ushort_t Bs[64 * 40];
  int m0 = blockIdx.x * 128;          // m = s*64 + b (z is (s,b)-major)
  int n0g = blockIdx.y * 64;
  int dir = n0g >> 10;
  int ncol0 = n0g & 1023;
  const ushort_t* Wb = wbf + (size_t)dir * 327680;
  const float* bias = dir ? bbv : bfv;
  int tid = threadIdx.x;
  int wv = tid >> 6, l = tid & 63;
  int lm = l & 15, lq = l >> 4;
  v4f acc[2][4];
  #pragma unroll
  for (int i = 0; i < 2; i++)
    #pragma unroll
    for (int j = 0; j < 4; j++) acc[i][j] = (v4f)0.f;

  for (int kc = 0; kc < 10; ++kc) {
    int k0 = kc * 32;
    #pragma unroll
    for (int rep = 0; rep < 2; ++rep) {
      int idx = rep * 256 + tid;
      int row = idx >> 2, q = idx & 3;
      *(ui4*)(As + row*40 + q*8) =
          *(const ui4*)(z + (size_t)(m0 + row)*D_ + k0 + q*8);
    }
    {
      int row = tid >> 2, q = tid & 3;
      *(ui4*)(Bs + row*40 + q*8) =
          *(const ui4*)(Wb + (size_t)(ncol0 + row)*D_ + k0 + q*8);
    }
    __syncthreads();
    v8s a0 = *(const v8s*)(As + (wv*32 + lm)*40 + lq*8);
    v8s a1 = *(const v8s*)(As + (wv*32 + 16 + lm)*40 + lq*8);
    #pragma unroll
    for (int nt = 0; nt < 4; ++nt) {
      v8s b = *(const v8s*)(Bs + (nt*16 + lm)*40 + lq*8);
      acc[0][nt] = __builtin_amdgcn_mfma_f32_16x16x32_bf16(a0, b, acc[0][nt], 0, 0, 0);
      acc[1][nt] = __builtin_amdgcn_mfma_f32_16x16x32_bf16(a1, b, acc[1][nt], 0, 0, 0);
    }
    __syncthreads();
  }
  // epilogue: r spans 4 consecutive batches -> one aligned us4 store each
  float bval[4];
  #pragma unroll
  for (int nt = 0; nt < 4; nt++) bval[nt] = bias[ncol0 + nt*16 + lm];
  #pragma unroll
  for (int mt = 0; mt < 2; mt++)
    #pragma unroll
    for (int nt = 0; nt < 4; nt++) {
      int m = m0 + wv*32 + mt*16 + lq*4;   // + r
      int b = m & 63, s = m >> 6;
      int col = ncol0 + nt*16 + lm;
      int gate = col >> 8, unit = col & 255;
      int w2 = unit >> 5, j = (unit >> 4) & 1, lm2 = unit & 15;
      int bg = b >> 4, bl = b & 15;        // bl multiple of 4
      us4 o;
      #pragma unroll
      for (int r = 0; r < 4; r++) o[r] = f2bf(acc[mt][nt][r] + bval[nt]);
      size_t idx = ((size_t)(dir*512 + s)*4 + bg)*16384
                 + (size_t)(((w2*2 + j)*4 + gate)*16 + lm2)*16 + bl;
      *(us4*)(gx2 + idx) = o;
    }
}

// ---------------- K3: intra-CU persistent LSTM v12 ----------------------------------------------
// v10 (static double-buffer hshA/hshB, 1399 us) + Areg[8] ONLY (+32 VGPR): passA stashes its
// A-fragments; passB's 8 redundant A re-reads are gone (MFMA A-operand from registers; B6/B7
// still from Wl LDS as in v10). Register model from the v11 spill: pool supports ~384/wave at
// 2 waves/SIMD; v10=320, v12=352 (fits), v11=384+ (spilled, 1399->3533). WRITE_SIZE is the
// spill tripwire: must stay ~37.4 MB.
#define LSTM_STEP(NN, HRD_ARR, HWR_ARR)                                                   \
  {                                                                                       \
    int n = (NN);                                                                         \
    int t = dir ? (511 - n) : n;                                                          \
    const ushort_t* hrd = &HRD_ARR[0][0];                                                 \
    ushort_t* hwr = &HWR_ARR[0][0];                                                       \
    if (n > 0) {                                                                          \
      int tp = dir ? (512 - n) : (n - 1);                                                 \
      ui4 hv = *(const ui4*)(hrd + db*PITCH + du);                                        \
      *(ui4*)(hs + ((size_t)(dir*512 + tp)*64 + bg*16 + db)*256 + du) = hv;               \
    }                                                                                     \
    const ushort_t* gnext = gx2                                                           \
        + ((size_t)(dir*512 + (dir ? (511 - ((n < 511) ? n+1 : n))                        \
                                   : ((n < 511) ? n+1 : n)))*4 + bg)*16384;               \
    v4f a0, a1, a2, a3;                                                                   \
    _Pragma("unroll")                                                                     \
    for (int r = 0; r < 4; r++) {                                                         \
      a0[r] = bf2f(gA[0][r]); a1[r] = bf2f(gA[1][r]);                                     \
      a2[r] = bf2f(gA[2][r]); a3[r] = bf2f(gA[3][r]);                                     \
    }                                                                                     \
    v8s Areg[8];                                                                          \
    {                                                                                     \
      v8s A = *(const v8s*)(hrd + lm*PITCH + lq*8);                                       \
      __builtin_amdgcn_s_setprio(1);                                                      \
      _Pragma("unroll")                                                                   \
      for (int kc = 0; kc < 8; kc++) {                                                    \
        v8s An = (kc < 7) ? *(const v8s*)(hrd + lm*PITCH + (kc+1)*32 + lq*8) : A;         \
        Areg[kc] = A;                                                                     \
        a0 = __builtin_amdgcn_mfma_f32_16x16x32_bf16(A, wfr[0][kc], a0, 0, 0, 0);         \
        a1 = __builtin_amdgcn_mfma_f32_16x16x32_bf16(A, wfr[1][kc], a1, 0, 0, 0);         \
        a2 = __builtin_amdgcn_mfma_f32_16x16x32_bf16(A, wfr[2][kc], a2, 0, 0, 0);         \
        a3 = __builtin_amdgcn_mfma_f32_16x16x32_bf16(A, wfr[3][kc], a3, 0, 0, 0);         \
        A = An;                                                                           \
      }                                                                                   \
      __builtin_amdgcn_s_setprio(0);                                                      \
    }                                                                                     \
    {                                                                                     \
      float hv0, hv1, hv2, hv3;                                                           \
      _Pragma("unroll")                                                                   \
      for (int r = 0; r < 4; r++) {                                                       \
        float ei = __expf(-a0[r]), ef = __expf(-a1[r]);                                   \
        float eg = __expf(2.f*a2[r]), eo = __expf(-a3[r]);                                \
        float p1 = (1.f + ei) * (eg + 1.f);                                               \
        float p2 = 1.f + ef;                                                              \
        float R  = __builtin_amdgcn_rcpf(p1 * p2);                                        \
        float ig = (eg - 1.f) * p2 * R;                                                   \
        float fa = p1 * R;                                                                \
        c0[r] = fa*c0[r] + ig;                                                            \
        float ec = __expf(2.f*c0[r]);                                                     \
        float hv = (ec - 1.f) * __builtin_amdgcn_rcpf((1.f + eo)*(ec + 1.f));             \
        if (r == 0) hv0 = hv; else if (r == 1) hv1 = hv;                                  \
        else if (r == 2) hv2 = hv; else hv3 = hv;                                         \
      }                                                                                   \
      unsigned int pk01, pk23;                                                            \
      asm("v_cvt_pk_bf16_f32 %0, %1, %2" : "=v"(pk01) : "v"(hv0), "v"(hv1));              \
      asm("v_cvt_pk_bf16_f32 %0, %1, %2" : "=v"(pk23) : "v"(hv2), "v"(hv3));              \
      hwr[(lq*4 + 0)*PITCH + u0] = (ushort_t)pk01;                                        \
      hwr[(lq*4 + 1)*PITCH + u0] = (ushort_t)(pk01 >> 16);                                \
      hwr[(lq*4 + 2)*PITCH + u0] = (ushort_t)pk23;                                        \
      hwr[(lq*4 + 3)*PITCH + u0] = (ushort_t)(pk23 >> 16);                                \
    }                                                                                     \
    _Pragma("unroll")                                                                     \
    for (int k = 0; k < 4; k++) gA[k] = *(const us4*)(gnext + goff[k]);                   \
    v4f a4, a5, a6, a7;                                                                   \
    _Pragma("unroll")                                                                     \
    for (int r = 0; r < 4; r++) {                                                         \
      a4[r] = bf2f(gB[0][r]); a5[r] = bf2f(gB[1][r]);                                     \
      a6[r] = bf2f(gB[2][r]); a7[r] = bf2f(gB[3][r]);                                     \
    }                                                                                     \
    {                                                                                     \
      v8s B6 = *(const v8s*)(Wl + ((size_t)((w*2 + 0)*8 + 0)*64 + l)*8);                  \
      v8s B7 = *(const v8s*)(Wl + ((size_t)((w*2 + 1)*8 + 0)*64 + l)*8);                  \
      __builtin_amdgcn_s_setprio(1);                                                      \
      _Pragma("unroll")                                                                   \
      for (int kc = 0; kc < 8; kc++) {                                                    \
        v8s B6n = (kc < 7) ? *(const v8s*)(Wl + ((size_t)((w*2 + 0)*8 + kc+1)*64 + l)*8) : B6; \
        v8s B7n = (kc < 7) ? *(const v8s*)(Wl + ((size_t)((w*2 + 1)*8 + kc+1)*64 + l)*8) : B7; \
        a4 = __builtin_amdgcn_mfma_f32_16x16x32_bf16(Areg[kc], wfr[4][kc], a4, 0, 0, 0);  \
        a5 = __builtin_amdgcn_mfma_f32_16x16x32_bf16(Areg[kc], wfr[5][kc], a5, 0, 0, 0);  \
        a6 = __builtin_amdgcn_mfma_f32_16x16x32_bf16(Areg[kc], B6, a6, 0, 0, 0);          \
        a7 = __builtin_amdgcn_mfma_f32_16x16x32_bf16(Areg[kc], B7, a7, 0, 0, 0);          \
        B6 = B6n; B7 = B7n;                                                               \
      }                                                                                   \
      __builtin_amdgcn_s_setprio(0);                                                      \
    }                                                                                     \
    {                                                                                     \
      float hv0, hv1, hv2, hv3;                                                           \
      _Pragma("unroll")                                                                   \
      for (int r = 0; r < 4; r++) {                                                       \
        float ei = __expf(-a4[r]), ef = __expf(-a5[r]);                                   \
        float eg = __expf(2.f*a6[r]), eo = __expf(-a7[r]);                                \
        float p1 = (1.f + ei) * (eg + 1.f);                                               \
        float p2 = 1.f + ef;                                                              \
        float R  = __builtin_amdgcn_rcpf(p1 * p2);                                        \
        float ig = (eg - 1.f) * p2 * R;                                                   \
        float fa = p1 * R;                                                                \
        c1[r] = fa*c1[r] + ig;                                                            \
        float ec = __expf(2.f*c1[r]);                                                     \
        float hv = (ec - 1.f) * __builtin_amdgcn_rcpf((1.f + eo)*(ec + 1.f));             \
        if (r == 0) hv0 = hv; else if (r == 1) hv1 = hv;                                  \
        else if (r == 2) hv2 = hv; else hv3 = hv;                                         \
      }                                                                                   \
      unsigned int pk01, pk23;                                                            \
      asm("v_cvt_pk_bf16_f32 %0, %1, %2" : "=v"(pk01) : "v"(hv0), "v"(hv1));              \
      asm("v_cvt_pk_bf16_f32 %0, %1, %2" : "=v"(pk23) : "v"(hv2), "v"(hv3));              \
      hwr[(lq*4 + 0)*PITCH + u1] = (ushort_t)pk01;                                        \
      hwr[(lq*4 + 1)*PITCH + u1] = (ushort_t)(pk01 >> 16);                                \
      hwr[(lq*4 + 2)*PITCH + u1] = (ushort_t)pk23;                                        \
      hwr[(lq*4 + 3)*PITCH + u1] = (ushort_t)(pk23 >> 16);                                \
    }                                                                                     \
    _Pragma("unroll")                                                                     \
    for (int k = 0; k < 4; k++) gB[k] = *(const us4*)(gnext + goff[4 + k]);               \
    block_sync_lds();                                                                     \
  }

__global__ __launch_bounds__(512, 2) void k_lstm(
    const ushort_t* __restrict__ gx2,
    const float* __restrict__ whhf, const float* __restrict__ whhb,
    ushort_t* __restrict__ hs)
{
  __shared__ ushort_t Wl[16 * 8 * 512];       // 128 KB
  __shared__ ushort_t hshA[16][PITCH];        // read at even n, written at odd n
  __shared__ ushort_t hshB[16][PITCH];        // read at odd n, written at even n
  int bid = blockIdx.x;
  int dir = bid >> 2, bg = bid & 3;
  int tid = threadIdx.x, w = tid >> 6, l = tid & 63;
  int lm = l & 15, lq = l >> 4;
  const float* W = dir ? whhb : whhf;

  for (int i = tid; i < 16 * PITCH; i += 512) {
    (&hshA[0][0])[i] = 0;
    (&hshB[0][0])[i] = 0;
  }
  // LDS W tiles: tile t=(w2,gsel): gate=2+gsel, rows gate*256 + w2*32 + 16 + lm2
  for (int idx = tid; idx < 16 * 8 * 64; idx += 512) {
    int t = idx >> 9, kc = (idx >> 6) & 7, ln = idx & 63;
    int lq2 = ln >> 4, lm2 = ln & 15;
    int w2 = t >> 1, gsel = t & 1;
    int row = (2 + gsel)*256 + w2*32 + 16 + lm2;
    const float* src = W + (size_t)row*256 + kc*32 + lq2*8;
    v8s f;
    #pragma unroll
    for (int jj = 0; jj < 8; jj++) f[jj] = (short)f2bf(src[jj]);
    *(v8s*)(Wl + ((size_t)(t*8 + kc)*64 + ln)*8) = f;
  }
  // register W tiles: ti 0..3 = gates i,f,g,o (lower 16 units); ti 4,5 = gates i,f (upper 16)
  v8s wfr[6][8];
  #pragma unroll
  for (int ti = 0; ti < 6; ti++) {
    int gate = (ti < 4) ? ti : (ti - 4);
    int jr = (ti < 4) ? 0 : 16;
    #pragma unroll
    for (int kc = 0; kc < 8; kc++) {
      const float* src = W + (size_t)(gate*256 + w*32 + jr + lm)*256 + kc*32 + lq*8;
      v8s f;
      #pragma unroll
      for (int jj = 0; jj < 8; jj++) f[jj] = (short)f2bf(src[jj]);
      wfr[ti][kc] = f;
    }
  }
  __syncthreads();

  float c0[4] = {0.f,0.f,0.f,0.f}, c1[4] = {0.f,0.f,0.f,0.f};
  int u0 = w*32 + lm, u1 = w*32 + 16 + lm;
  int goff[8];
  #pragma unroll
  for (int j = 0; j < 2; j++)
    #pragma unroll
    for (int ga = 0; ga < 4; ga++)
      goff[j*4 + ga] = (((w*2 + j)*4 + ga)*16 + lm)*16 + lq*4;
  // hs-dump lane mapping: one 16B slot per lane covers hsh[16][256]
  int db = tid >> 5, du = (tid & 31) * 8;

  us4 gA[4], gB[4];
  {
    int t0 = dir ? 511 : 0;
    const ushort_t* gb = gx2 + ((size_t)(dir*512 + t0)*4 + bg)*16384;
    #pragma unroll
    for (int k = 0; k < 4; k++) gA[k] = *(const us4*)(gb + goff[k]);
    #pragma unroll
    for (int k = 0; k < 4; k++) gB[k] = *(const us4*)(gb + goff[4 + k]);
  }

  for (int n2 = 0; n2 < 512; n2 += 2) {
    LSTM_STEP(n2,     hshA, hshB);   // read A (parity 0), write B
    LSTM_STEP(n2 + 1, hshB, hshA);   // read B (parity 1), write A
  }
  // final h dump: h at t_last was written by body n=511 into hshA (parity 0)
  {
    int tp = dir ? 0 : 511;
    const ushort_t* hfin = &hshA[0][0];
    ui4 hv = *(const ui4*)(hfin + db*PITCH + du);
    *(ui4*)(hs + ((size_t)(dir*512 + tp)*64 + bg*16 + db)*256 + du) = hv;
  }
}

// ---------------- K4: emissions[b][s][17] = [h_f, h_b] @ cls_w^T + cls_b (fp32) ----------------
__global__ __launch_bounds__(256) void k_emis(
    const ushort_t* __restrict__ hs, const float* __restrict__ clsw,
    const float* __restrict__ clsb, float* __restrict__ emis)
{
  int tid = threadIdx.x;
  if (tid >= 255) return;
  int wi = blockIdx.x * 15 + tid / 17;
  int tau = tid % 17;
  if (wi >= B_ * S_) return;
  int b = wi >> 9, s = wi & 511;
  const ushort_t* hf  = hs + ((size_t)s*64 + b) * 256;
  const ushort_t* hbk = hs + (((size_t)512 + s)*64 + b) * 256;
  const float* cwf = clsw + (size_t)tau * 512;
  const float* cwb = cwf + 256;
  union { unsigned int u; float f; } bc;
  float acc = clsb[tau];
  #pragma unroll 4
  for (int k = 0; k < 256; k += 8) {
    ui4 h8 = *(const ui4*)(hf + k);
    f4 wa = *(const f4*)(cwf + k); f4 wb = *(const f4*)(cwf + k + 4);
    bc.u = h8[0] << 16;           acc += bc.f * wa[0];
    bc.u = h8[0] & 0xffff0000u;   acc += bc.f * wa[1];
    bc.u = h8[1] << 16;           acc += bc.f * wa[2];
    bc.u = h8[1] & 0xffff0000u;   acc += bc.f * wa[3];
    bc.u = h8[2] << 16;           acc += bc.f * wb[0];
    bc.u = h8[2] & 0xffff0000u;   acc += bc.f * wb[1];
    bc.u = h8[3] << 16;           acc += bc.f * wb[2];
    bc.u = h8[3] & 0xffff0000u;   acc += bc.f * wb[3];
  }
  #pragma unroll 4
  for (int k = 0; k < 256; k += 8) {
    ui4 h8 = *(const ui4*)(hbk + k);
    f4 wa = *(const f4*)(cwb + k); f4 wb = *(const f4*)(cwb + k + 4);
    bc.u = h8[0] << 16;           acc += bc.f * wa[0];
    bc.u = h8[0] & 0xffff0000u;   acc += bc.f * wa[1];
    bc.u = h8[1] << 16;           acc += bc.f * wa[2];
    bc.u = h8[1] & 0xffff0000u;   acc += bc.f * wa[3];
    bc.u = h8[2] << 16;           acc += bc.f * wb[0];
    bc.u = h8[2] & 0xffff0000u;   acc += bc.f * wb[1];
    bc.u = h8[3] << 16;           acc += bc.f * wb[2];
    bc.u = h8[3] & 0xffff0000u;   acc += bc.f * wb[3];
  }
  emis[(size_t)wi * 17 + tau] = acc;
}

// ---------------- K5: CRF — 64 blocks (one per batch): wave0 = loss fwd, wave1 = viterbi --------
__global__ __launch_bounds__(128) void k_crf(
    const float* __restrict__ emis, const int* __restrict__ labels,
    const int* __restrict__ mask, const float* __restrict__ startt,
    const float* __restrict__ endt, const float* __restrict__ trans,
    float* __restrict__ lossp, float* __restrict__ outp)
{
  __shared__ unsigned char bps[511][17];
  int b = blockIdx.x;
  int tid = threadIdx.x, wv = tid >> 6, l = tid & 63;
  int tauc = (l < 17) ? l : 0;
  float tc[17];
  #pragma unroll
  for (int i = 0; i < 17; i++) tc[i] = trans[i*17 + tauc];
  const float* eb = emis + (size_t)b * 512 * 17;
  float alpha = startt[tauc] + eb[tauc];
  if (l >= 17) alpha = -3e30f;

  if (wv == 0) {
    float e_cur = (l < 17) ? eb[17 + l] : 0.f;
    int   m_cur = mask[b*512 + 1];
    for (int t = 1; t < 512; t++) {
      float e_nxt = 0.f; int m_nxt = 1;
      if (t < 511) {
        e_nxt = (l < 17) ? eb[(t+1)*17 + l] : 0.f;
        m_nxt = mask[b*512 + t + 1];
      }
      float arr[17];
      #pragma unroll
      for (int i = 0; i < 17; i++) arr[i] = __shfl(alpha, i) + tc[i];
      // depth-5 fmax tree
      float t8[8];
      #pragma unroll
      for (int i = 0; i < 8; i++) t8[i] = fmaxf(arr[2*i], arr[2*i+1]);
      float t4a = fmaxf(t8[0], t8[1]), t4b = fmaxf(t8[2], t8[3]);
      float t4c = fmaxf(t8[4], t8[5]), t4d = fmaxf(t8[6], t8[7]);
      float mx = fmaxf(fmaxf(fmaxf(t4a, t4b), fmaxf(t4c, t4d)), arr[16]);
      // exp + depth-5 add tree
      float ex[17];
      #pragma unroll
      for (int i = 0; i < 17; i++) ex[i] = __expf(arr[i] - mx);
      float s8[8];
      #pragma unroll
      for (int i = 0; i < 8; i++) s8[i] = ex[2*i] + ex[2*i+1];
      float ss = (((s8[0] + s8[1]) + (s8[2] + s8[3]))
               + ((s8[4] + s8[5]) + (s8[6] + s8[7]))) + ex[16];
      float nxt = mx + __logf(ss) + e_cur;
      if (m_cur > 0 && l < 17) alpha = nxt;
      e_cur = e_nxt; m_cur = m_nxt;
    }
    float a2 = (l < 17) ? (alpha + endt[l]) : -3e30f;
    float mx = a2;
    #pragma unroll
    for (int o = 32; o > 0; o >>= 1) mx = fmaxf(mx, __shfl_xor(mx, o));
    float ss = (l < 17) ? __expf(a2 - mx) : 0.f;
    #pragma unroll
    for (int o = 32; o > 0; o >>= 1) ss += __shfl_xor(ss, o);
    float denom = mx + __logf(ss);
    float ns = 0.f; int msum = 0;
    for (int t = l; t < 512; t += 64) {
      int tg = labels[b*512 + t];
      int mt = mask[b*512 + t];
      msum += (mt > 0);
      if (mt > 0) {
        ns += eb[t*17 + tg];
        if (t > 0) ns += trans[labels[b*512 + t - 1]*17 + tg];
      }
    }
    #pragma unroll
    for (int o = 32; o > 0; o >>= 1) { ns += __shfl_xor(ns, o); msum += __shfl_xor(msum, o); }
    if (l == 0) {
      int lidx = msum - 1;
      float num = ns + startt[labels[b*512]] + endt[labels[b*512 + lidx]];
      lossp[b] = num - denom;
    }
  } else {
    float e_cur = (l < 17) ? eb[17 + l] : 0.f;
    int   m_cur = mask[b*512 + 1];
    for (int t = 1; t < 512; t++) {
      float e_nxt = 0.f; int m_nxt = 1;
      if (t < 511) {
        e_nxt = (l < 17) ? eb[(t+1)*17 + l] : 0.f;
        m_nxt = mask[b*512 + t + 1];
      }
      float av[17];
      #pragma unroll
      for (int i = 0; i < 17; i++) av[i] = __shfl(alpha, i) + tc[i];
      // depth-5 argmax tournament, left-priority (>=): first-max == np.argmax
      float v8l[8]; int i8[8];
      #pragma unroll
      for (int i = 0; i < 8; i++) {
        int take = (av[2*i] >= av[2*i+1]);
        v8l[i] = take ? av[2*i] : av[2*i+1];
        i8[i]  = take ? 2*i : 2*i+1;
      }
      float v4l[4]; int i4[4];
      #pragma unroll
      for (int i = 0; i < 4; i++) {
        int take = (v8l[2*i] >= v8l[2*i+1]);
        v4l[i] = take ? v8l[2*i] : v8l[2*i+1];
        i4[i]  = take ? i8[2*i] : i8[2*i+1];
      }
      float v2a = (v4l[0] >= v4l[1]) ? v4l[0] : v4l[1];
      int   i2a = (v4l[0] >= v4l[1]) ? i4[0] : i4[1];
      float v2b = (v4l[2] >= v4l[3]) ? v4l[2] : v4l[3];
      int   i2b = (v4l[2] >= v4l[3]) ? i4[2] : i4[3];
      float v1 = (v2a >= v2b) ? v2a : v2b;
      int   i1 = (v2a >= v2b) ? i2a : i2b;
      float best = (v1 >= av[16]) ? v1 : av[16];
      int   bi   = (v1 >= av[16]) ? i1 : 16;
      float nxt = best + e_cur;
      int bpv = (m_cur > 0) ? bi : l;
      if (l < 17) {
        bps[t-1][l] = (unsigned char)bpv;
        if (m_cur > 0) alpha = nxt;
      }
      e_cur = e_nxt; m_cur = m_nxt;
    }
    float a2 = (l < 17) ? (alpha + endt[l]) : -3e30f;
    float av[17];
    #pragma unroll
    for (int i = 0; i < 17; i++) av[i] = __shfl(a2, i);
    int bt = 0; float bv2 = av[0];
    #pragma unroll
    for (int i = 1; i < 17; i++) if (av[i] > bv2) { bv2 = av[i]; bt = i; }
    if (l == 0) outp[1 + b*512 + 511] = (float)bt;
    int tg = bt;
    for (int t = 510; t >= 0; --t) {
      tg = bps[t][tg];
      if (l == 0) outp[1 + b*512 + t] = (float)tg;
    }
  }
}

// ---------------- K6: loss = -mean(num - denom), fp32 ----------------
__global__ __launch_bounds__(64) void k_final(const float* __restrict__ lossp,
                                              float* __restrict__ outp)
{
  int l = threadIdx.x;
  float v = lossp[l];
  #pragma unroll
  for (int o = 32; o > 0; o >>= 1) v += __shfl_xor(v, o);
  if (l == 0) outp[0] = -(v / 64.f);
}

// ---------------- host ----------------
extern "C" void kernel_launch(void* const* d_in, const int* in_sizes, int n_in,
                              void* d_out, int out_size, void* d_ws, size_t ws_size,
                              hipStream_t stream)
{
  (void)in_sizes; (void)n_in; (void)out_size; (void)ws_size;
  const int*   tok   = (const int*)d_in[0];
  const int*   ctok  = (const int*)d_in[1];
  const int*   labels= (const int*)d_in[2];
  const int*   amask = (const int*)d_in[3];
  const float* wemb  = (const float*)d_in[4];
  const float* cemb  = (const float*)d_in[5];
  const float* convw = (const float*)d_in[6];
  const float* convb = (const float*)d_in[7];
  const float* wihf  = (const float*)d_in[8];
  const float* whhf  = (const float*)d_in[9];
  const float* bfv   = (const float*)d_in[10];
  const float* wihb  = (const float*)d_in[11];
  const float* whhb  = (const float*)d_in[12];
  const float* bbv   = (const float*)d_in[13];
  const float* clsw  = (const float*)d_in[14];
  const float* clsb  = (const float*)d_in[15];
  const float* stt   = (const float*)d_in[16];
  const float* ent   = (const float*)d_in[17];
  const float* trn   = (const float*)d_in[18];

  // workspace layout (bytes): [z 20,971,520][gx2 134,217,728][hs 33,554,432]
  //                           [emis 2,228,224][lossp 256]
  // W_ih bf16 (1.3 MB) aliases the START of the hs region: written by k_wcvt and read by
  // k_gemm_gx, both of which complete (stream-ordered) before k_lstm writes hs.
  char* ws = (char*)d_ws;
  ushort_t* z    = (ushort_t*)(ws);
  ushort_t* gx2  = (ushort_t*)(ws + 20971520);
  ushort_t* hs   = (ushort_t*)(ws + 155189248);
  float*    emis = (float*)(ws + 188743680);
  float*    lossp= (float*)(ws + 190971904);
  ushort_t* wbf  = (ushort_t*)(ws + 155189248);   // aliases hs (dead until k_lstm)

  hipLaunchKernelGGL(k_wcvt,    dim3(640),         dim3(256), 0, stream,
                     wihf, wihb, wbf);
  hipLaunchKernelGGL(k_embed,   dim3(B_*S_/4),     dim3(256), 0, stream,
                     tok, ctok, wemb, cemb, convw, convb, z);
  hipLaunchKernelGGL(k_gemm_gx, dim3(256, 32),     dim3(256), 0, stream,
                     z, wbf, bfv, bbv, gx2);
  hipLaunchKernelGGL(k_lstm,    dim3(8),           dim3(512), 0, stream,
                     gx2, whhf, whhb, hs);
  hipLaunchKernelGGL(k_emis,    dim3((B_*S_ + 14)/15), dim3(256), 0, stream,
                     hs, clsw, clsb, emis);
  hipLaunchKernelGGL(k_crf,     dim3(64),          dim3(128), 0, stream,
                     emis, labels, amask, stt, ent, trn, lossp, (float*)d_out);
  hipLaunchKernelGGL(k_final,   dim3(1),           dim3(64),  0, stream,
                     lossp, (float*)d_out);
}

// Round 13
// 1983.967 us; speedup vs baseline: 2.0772x; 1.2769x over previous
//
#include <hip/hip_runtime.h>

// ---------------- problem constants ----------------
#define B_  64
#define S_  512
#define L_  16
#define WD_ 200
#define CD_ 30
#define FN_ 4
#define KW_ 3
#define H_  256
#define T_  17
#define D_  320   // WD + CD*FN
#define PITCH 280  // h-row pitch in ushorts: 140 dwords == 12 mod 32 -> conflict-free b128

typedef unsigned short ushort_t;
typedef __attribute__((ext_vector_type(8))) short v8s;   // bf16x8 MFMA frag
typedef __attribute__((ext_vector_type(4))) float v4f;   // fp32x4 MFMA acc
typedef __attribute__((ext_vector_type(4))) float f4;
typedef __attribute__((ext_vector_type(4))) unsigned int ui4;
typedef __attribute__((ext_vector_type(4))) unsigned short us4;

__device__ __forceinline__ float bf2f(unsigned short u) {
  union { unsigned int i; float f; } v; v.i = ((unsigned int)u) << 16; return v.f;
}
__device__ __forceinline__ unsigned short f2bf(float f) {
  union { float f; unsigned int i; } v; v.f = f;
  unsigned int r = v.i + 0x7fffu + ((v.i >> 16) & 1u);   // RNE
  return (unsigned short)(r >> 16);
}
// barrier that does NOT drain vmcnt (keeps global prefetch loads in flight)
__device__ __forceinline__ void block_sync_lds() {
  __asm__ volatile("s_waitcnt lgkmcnt(0)\n\ts_barrier" ::: "memory");
}

// ---------------- K0: one-time W_ih f32->bf16 conversion (into dead hs region) -----------------
__global__ __launch_bounds__(256) void k_wcvt(
    const float* __restrict__ wf, const float* __restrict__ wb,
    ushort_t* __restrict__ wbf)
{
  int idx = (blockIdx.x * 256 + threadIdx.x) * 4;   // 640 blocks: covers 2*1024*320
  const float* src = (idx < 327680) ? (wf + idx) : (wb + (idx - 327680));
  f4 v = *(const f4*)src;
  us4 o; o[0]=f2bf(v[0]); o[1]=f2bf(v[1]); o[2]=f2bf(v[2]); o[3]=f2bf(v[3]);
  *(us4*)(wbf + idx) = o;
}

// ---------------- K1: word emb (f32->bf16) + char CNN + maxpool -> z [(s,b)-major, 320] ---------
__global__ __launch_bounds__(256) void k_embed(
    const int* __restrict__ tok, const int* __restrict__ ctok,
    const float* __restrict__ wemb, const float* __restrict__ cemb,
    const float* __restrict__ cw, const float* __restrict__ cb,
    ushort_t* __restrict__ z)
{
  int g = threadIdx.x >> 6;           // word slot in block
  int l = threadIdx.x & 63;
  int w = blockIdx.x * 4 + g;         // input word index = b*S + s
  int b = w >> 9, s = w & 511;
  size_t ro = (size_t)s * 64 + b;     // OUTPUT row: (s,b)-major
  __shared__ float ce[4][L_][32];
  if (l < L_) {
    int cid = ctok[w * L_ + l];
    const float* row = cemb + (size_t)cid * CD_;
    #pragma unroll
    for (int j = 0; j < CD_; ++j) ce[g][l][j] = row[j];
  }
  int t = tok[w];
  const f4* src = (const f4*)(wemb + (size_t)t * WD_);
  if (l < 50) {
    f4 v = src[l];
    us4 o; o[0]=f2bf(v[0]); o[1]=f2bf(v[1]); o[2]=f2bf(v[2]); o[3]=f2bf(v[3]);
    *(us4*)(z + ro * D_ + l*4) = o;
  }
  __syncthreads();
  for (int oc = l; oc < CD_ * FN_; oc += 64) {
    int c = oc >> 2;
    float w0 = cw[oc*3+0], w1 = cw[oc*3+1], w2 = cw[oc*3+2];
    float mx = -3e30f;
    #pragma unroll
    for (int p = 0; p < L_ - KW_ + 1; ++p) {
      float sv = ce[g][p][c]*w0 + ce[g][p+1][c]*w1 + ce[g][p+2][c]*w2;
      mx = fmaxf(mx, sv);
    }
    z[ro * D_ + WD_ + oc] = f2bf(mx + cb[oc]);
  }
}

// ---------------- K2: gx2 = z @ W_ih^T + b, packed for k_lstm lane-slots (us4 stores) -----------
// gx2 idx = ((dir*512+s)*4+bg)*16384 + (((w2*2+j)*4+gate)*16+lm2)*16 + b_local (bf16)
__global__ __launch_bounds__(256) void k_gemm_gx(
    const ushort_t* __restrict__ z, const ushort_t* __restrict__ wbf,
    const float* __restrict__ bfv, const float* __restrict__ bbv,
    ushort_t* __restrict__ gx2)
{
  __shared__ ushort_t As[128 * 40];
  __shared__ ushort_t Bs[64 * 40];
  int m0 = blockIdx.x * 128;          // m = s*64 + b (z is (s,b)-major)
  int n0g = blockIdx.y * 64;
  int dir = n0g >> 10;
  int ncol0 = n0g & 1023;
  const ushort_t* Wb = wbf + (size_t)dir * 327680;
  const float* bias = dir ? bbv : bfv;
  int tid = threadIdx.x;
  int wv = tid >> 6, l = tid & 63;
  int lm = l & 15, lq = l >> 4;
  v4f acc[2][4];
  #pragma unroll
  for (int i = 0; i < 2; i++)
    #pragma unroll
    for (int j = 0; j < 4; j++) acc[i][j] = (v4f)0.f;

  for (int kc = 0; kc < 10; ++kc) {
    int k0 = kc * 32;
    #pragma unroll
    for (int rep = 0; rep < 2; ++rep) {
      int idx = rep * 256 + tid;
      int row = idx >> 2, q = idx & 3;
      *(ui4*)(As + row*40 + q*8) =
          *(const ui4*)(z + (size_t)(m0 + row)*D_ + k0 + q*8);
    }
    {
      int row = tid >> 2, q = tid & 3;
      *(ui4*)(Bs + row*40 + q*8) =
          *(const ui4*)(Wb + (size_t)(ncol0 + row)*D_ + k0 + q*8);
    }
    __syncthreads();
    v8s a0 = *(const v8s*)(As + (wv*32 + lm)*40 + lq*8);
    v8s a1 = *(const v8s*)(As + (wv*32 + 16 + lm)*40 + lq*8);
    #pragma unroll
    for (int nt = 0; nt < 4; ++nt) {
      v8s b = *(const v8s*)(Bs + (nt*16 + lm)*40 + lq*8);
      acc[0][nt] = __builtin_amdgcn_mfma_f32_16x16x32_bf16(a0, b, acc[0][nt], 0, 0, 0);
      acc[1][nt] = __builtin_amdgcn_mfma_f32_16x16x32_bf16(a1, b, acc[1][nt], 0, 0, 0);
    }
    __syncthreads();
  }
  // epilogue: r spans 4 consecutive batches -> one aligned us4 store each
  float bval[4];
  #pragma unroll
  for (int nt = 0; nt < 4; nt++) bval[nt] = bias[ncol0 + nt*16 + lm];
  #pragma unroll
  for (int mt = 0; mt < 2; mt++)
    #pragma unroll
    for (int nt = 0; nt < 4; nt++) {
      int m = m0 + wv*32 + mt*16 + lq*4;   // + r
      int b = m & 63, s = m >> 6;
      int col = ncol0 + nt*16 + lm;
      int gate = col >> 8, unit = col & 255;
      int w2 = unit >> 5, j = (unit >> 4) & 1, lm2 = unit & 15;
      int bg = b >> 4, bl = b & 15;        // bl multiple of 4
      us4 o;
      #pragma unroll
      for (int r = 0; r < 4; r++) o[r] = f2bf(acc[mt][nt][r] + bval[nt]);
      size_t idx = ((size_t)(dir*512 + s)*4 + bg)*16384
                 + (size_t)(((w2*2 + j)*4 + gate)*16 + lm2)*16 + bl;
      *(us4*)(gx2 + idx) = o;
    }
}

// ---------------- K3: intra-CU persistent LSTM v10 (PINNED best: 1399 us, R10) ------------------
// Static double-buffer (hshA/hshB named arrays + 2x unroll) gives provable no-alias between
// epi h-stores and pass h-reads -> compiler interleaves VALU epilogues into MFMA shadows
// (MfmaUtil 0.77 -> 0.97 vs v6). FOUR structural probes all regressed from here:
//   v8 fused passes 1872 | v9 early prefetch 2124 | v11 all-reg W (spill) 3533 | v12 Areg 1936.
// The scheduler's emergent interleave IS the asset. DO NOT perturb the phase structure.
#define LSTM_STEP(NN, HRD_ARR, HWR_ARR)                                                   \
  {                                                                                       \
    int n = (NN);                                                                         \
    int t = dir ? (511 - n) : n;                                                          \
    const ushort_t* hrd = &HRD_ARR[0][0];                                                 \
    ushort_t* hwr = &HWR_ARR[0][0];                                                       \
    if (n > 0) {                                                                          \
      int tp = dir ? (512 - n) : (n - 1);                                                 \
      ui4 hv = *(const ui4*)(hrd + db*PITCH + du);                                        \
      *(ui4*)(hs + ((size_t)(dir*512 + tp)*64 + bg*16 + db)*256 + du) = hv;               \
    }                                                                                     \
    const ushort_t* gnext = gx2                                                           \
        + ((size_t)(dir*512 + (dir ? (511 - ((n < 511) ? n+1 : n))                        \
                                   : ((n < 511) ? n+1 : n)))*4 + bg)*16384;               \
    v4f a0, a1, a2, a3;                                                                   \
    _Pragma("unroll")                                                                     \
    for (int r = 0; r < 4; r++) {                                                         \
      a0[r] = bf2f(gA[0][r]); a1[r] = bf2f(gA[1][r]);                                     \
      a2[r] = bf2f(gA[2][r]); a3[r] = bf2f(gA[3][r]);                                     \
    }                                                                                     \
    {                                                                                     \
      v8s A = *(const v8s*)(hrd + lm*PITCH + lq*8);                                       \
      __builtin_amdgcn_s_setprio(1);                                                      \
      _Pragma("unroll")                                                                   \
      for (int kc = 0; kc < 8; kc++) {                                                    \
        v8s An = (kc < 7) ? *(const v8s*)(hrd + lm*PITCH + (kc+1)*32 + lq*8) : A;         \
        a0 = __builtin_amdgcn_mfma_f32_16x16x32_bf16(A, wfr[0][kc], a0, 0, 0, 0);         \
        a1 = __builtin_amdgcn_mfma_f32_16x16x32_bf16(A, wfr[1][kc], a1, 0, 0, 0);         \
        a2 = __builtin_amdgcn_mfma_f32_16x16x32_bf16(A, wfr[2][kc], a2, 0, 0, 0);         \
        a3 = __builtin_amdgcn_mfma_f32_16x16x32_bf16(A, wfr[3][kc], a3, 0, 0, 0);         \
        A = An;                                                                           \
      }                                                                                   \
      __builtin_amdgcn_s_setprio(0);                                                      \
    }                                                                                     \
    {                                                                                     \
      float hv0, hv1, hv2, hv3;                                                           \
      _Pragma("unroll")                                                                   \
      for (int r = 0; r < 4; r++) {                                                       \
        float ei = __expf(-a0[r]), ef = __expf(-a1[r]);                                   \
        float eg = __expf(2.f*a2[r]), eo = __expf(-a3[r]);                                \
        float p1 = (1.f + ei) * (eg + 1.f);                                               \
        float p2 = 1.f + ef;                                                              \
        float R  = __builtin_amdgcn_rcpf(p1 * p2);                                        \
        float ig = (eg - 1.f) * p2 * R;                                                   \
        float fa = p1 * R;                                                                \
        c0[r] = fa*c0[r] + ig;                                                            \
        float ec = __expf(2.f*c0[r]);                                                     \
        float hv = (ec - 1.f) * __builtin_amdgcn_rcpf((1.f + eo)*(ec + 1.f));             \
        if (r == 0) hv0 = hv; else if (r == 1) hv1 = hv;                                  \
        else if (r == 2) hv2 = hv; else hv3 = hv;                                         \
      }                                                                                   \
      unsigned int pk01, pk23;                                                            \
      asm("v_cvt_pk_bf16_f32 %0, %1, %2" : "=v"(pk01) : "v"(hv0), "v"(hv1));              \
      asm("v_cvt_pk_bf16_f32 %0, %1, %2" : "=v"(pk23) : "v"(hv2), "v"(hv3));              \
      hwr[(lq*4 + 0)*PITCH + u0] = (ushort_t)pk01;                                        \
      hwr[(lq*4 + 1)*PITCH + u0] = (ushort_t)(pk01 >> 16);                                \
      hwr[(lq*4 + 2)*PITCH + u0] = (ushort_t)pk23;                                        \
      hwr[(lq*4 + 3)*PITCH + u0] = (ushort_t)(pk23 >> 16);                                \
    }                                                                                     \
    _Pragma("unroll")                                                                     \
    for (int k = 0; k < 4; k++) gA[k] = *(const us4*)(gnext + goff[k]);                   \
    v4f a4, a5, a6, a7;                                                                   \
    _Pragma("unroll")                                                                     \
    for (int r = 0; r < 4; r++) {                                                         \
      a4[r] = bf2f(gB[0][r]); a5[r] = bf2f(gB[1][r]);                                     \
      a6[r] = bf2f(gB[2][r]); a7[r] = bf2f(gB[3][r]);                                     \
    }                                                                                     \
    {                                                                                     \
      v8s A = *(const v8s*)(hrd + lm*PITCH + lq*8);                                       \
      v8s B6 = *(const v8s*)(Wl + ((size_t)((w*2 + 0)*8 + 0)*64 + l)*8);                  \
      v8s B7 = *(const v8s*)(Wl + ((size_t)((w*2 + 1)*8 + 0)*64 + l)*8);                  \
      __builtin_amdgcn_s_setprio(1);                                                      \
      _Pragma("unroll")                                                                   \
      for (int kc = 0; kc < 8; kc++) {                                                    \
        v8s An = (kc < 7) ? *(const v8s*)(hrd + lm*PITCH + (kc+1)*32 + lq*8) : A;         \
        v8s B6n = (kc < 7) ? *(const v8s*)(Wl + ((size_t)((w*2 + 0)*8 + kc+1)*64 + l)*8) : B6; \
        v8s B7n = (kc < 7) ? *(const v8s*)(Wl + ((size_t)((w*2 + 1)*8 + kc+1)*64 + l)*8) : B7; \
        a4 = __builtin_amdgcn_mfma_f32_16x16x32_bf16(A, wfr[4][kc], a4, 0, 0, 0);         \
        a5 = __builtin_amdgcn_mfma_f32_16x16x32_bf16(A, wfr[5][kc], a5, 0, 0, 0);         \
        a6 = __builtin_amdgcn_mfma_f32_16x16x32_bf16(A, B6, a6, 0, 0, 0);                 \
        a7 = __builtin_amdgcn_mfma_f32_16x16x32_bf16(A, B7, a7, 0, 0, 0);                 \
        A = An; B6 = B6n; B7 = B7n;                                                       \
      }                                                                                   \
      __builtin_amdgcn_s_setprio(0);                                                      \
    }                                                                                     \
    {                                                                                     \
      float hv0, hv1, hv2, hv3;                                                           \
      _Pragma("unroll")                                                                   \
      for (int r = 0; r < 4; r++) {                                                       \
        float ei = __expf(-a4[r]), ef = __expf(-a5[r]);                                   \
        float eg = __expf(2.f*a6[r]), eo = __expf(-a7[r]);                                \
        float p1 = (1.f + ei) * (eg + 1.f);                                               \
        float p2 = 1.f + ef;                                                              \
        float R  = __builtin_amdgcn_rcpf(p1 * p2);                                        \
        float ig = (eg - 1.f) * p2 * R;                                                   \
        float fa = p1 * R;                                                                \
        c1[r] = fa*c1[r] + ig;                                                            \
        float ec = __expf(2.f*c1[r]);                                                     \
        float hv = (ec - 1.f) * __builtin_amdgcn_rcpf((1.f + eo)*(ec + 1.f));             \
        if (r == 0) hv0 = hv; else if (r == 1) hv1 = hv;                                  \
        else if (r == 2) hv2 = hv; else hv3 = hv;                                         \
      }                                                                                   \
      unsigned int pk01, pk23;                                                            \
      asm("v_cvt_pk_bf16_f32 %0, %1, %2" : "=v"(pk01) : "v"(hv0), "v"(hv1));              \
      asm("v_cvt_pk_bf16_f32 %0, %1, %2" : "=v"(pk23) : "v"(hv2), "v"(hv3));              \
      hwr[(lq*4 + 0)*PITCH + u1] = (ushort_t)pk01;                                        \
      hwr[(lq*4 + 1)*PITCH + u1] = (ushort_t)(pk01 >> 16);                                \
      hwr[(lq*4 + 2)*PITCH + u1] = (ushort_t)pk23;                                        \
      hwr[(lq*4 + 3)*PITCH + u1] = (ushort_t)(pk23 >> 16);                                \
    }                                                                                     \
    _Pragma("unroll")                                                                     \
    for (int k = 0; k < 4; k++) gB[k] = *(const us4*)(gnext + goff[4 + k]);               \
    block_sync_lds();                                                                     \
  }

__global__ __launch_bounds__(512, 2) void k_lstm(
    const ushort_t* __restrict__ gx2,
    const float* __restrict__ whhf, const float* __restrict__ whhb,
    ushort_t* __restrict__ hs)
{
  __shared__ ushort_t Wl[16 * 8 * 512];       // 128 KB
  __shared__ ushort_t hshA[16][PITCH];        // read at even n, written at odd n
  __shared__ ushort_t hshB[16][PITCH];        // read at odd n, written at even n
  int bid = blockIdx.x;
  int dir = bid >> 2, bg = bid & 3;
  int tid = threadIdx.x, w = tid >> 6, l = tid & 63;
  int lm = l & 15, lq = l >> 4;
  const float* W = dir ? whhb : whhf;

  for (int i = tid; i < 16 * PITCH; i += 512) {
    (&hshA[0][0])[i] = 0;
    (&hshB[0][0])[i] = 0;
  }
  // LDS W tiles: tile t=(w2,gsel): gate=2+gsel, rows gate*256 + w2*32 + 16 + lm2
  for (int idx = tid; idx < 16 * 8 * 64; idx += 512) {
    int t = idx >> 9, kc = (idx >> 6) & 7, ln = idx & 63;
    int lq2 = ln >> 4, lm2 = ln & 15;
    int w2 = t >> 1, gsel = t & 1;
    int row = (2 + gsel)*256 + w2*32 + 16 + lm2;
    const float* src = W + (size_t)row*256 + kc*32 + lq2*8;
    v8s f;
    #pragma unroll
    for (int jj = 0; jj < 8; jj++) f[jj] = (short)f2bf(src[jj]);
    *(v8s*)(Wl + ((size_t)(t*8 + kc)*64 + ln)*8) = f;
  }
  // register W tiles: ti 0..3 = gates i,f,g,o (lower 16 units); ti 4,5 = gates i,f (upper 16)
  v8s wfr[6][8];
  #pragma unroll
  for (int ti = 0; ti < 6; ti++) {
    int gate = (ti < 4) ? ti : (ti - 4);
    int jr = (ti < 4) ? 0 : 16;
    #pragma unroll
    for (int kc = 0; kc < 8; kc++) {
      const float* src = W + (size_t)(gate*256 + w*32 + jr + lm)*256 + kc*32 + lq*8;
      v8s f;
      #pragma unroll
      for (int jj = 0; jj < 8; jj++) f[jj] = (short)f2bf(src[jj]);
      wfr[ti][kc] = f;
    }
  }
  __syncthreads();

  float c0[4] = {0.f,0.f,0.f,0.f}, c1[4] = {0.f,0.f,0.f,0.f};
  int u0 = w*32 + lm, u1 = w*32 + 16 + lm;
  int goff[8];
  #pragma unroll
  for (int j = 0; j < 2; j++)
    #pragma unroll
    for (int ga = 0; ga < 4; ga++)
      goff[j*4 + ga] = (((w*2 + j)*4 + ga)*16 + lm)*16 + lq*4;
  // hs-dump lane mapping: one 16B slot per lane covers hsh[16][256]
  int db = tid >> 5, du = (tid & 31) * 8;

  us4 gA[4], gB[4];
  {
    int t0 = dir ? 511 : 0;
    const ushort_t* gb = gx2 + ((size_t)(dir*512 + t0)*4 + bg)*16384;
    #pragma unroll
    for (int k = 0; k < 4; k++) gA[k] = *(const us4*)(gb + goff[k]);
    #pragma unroll
    for (int k = 0; k < 4; k++) gB[k] = *(const us4*)(gb + goff[4 + k]);
  }

  for (int n2 = 0; n2 < 512; n2 += 2) {
    LSTM_STEP(n2,     hshA, hshB);   // read A (parity 0), write B
    LSTM_STEP(n2 + 1, hshB, hshA);   // read B (parity 1), write A
  }
  // final h dump: h at t_last was written by body n=511 into hshA (parity 0)
  {
    int tp = dir ? 0 : 511;
    const ushort_t* hfin = &hshA[0][0];
    ui4 hv = *(const ui4*)(hfin + db*PITCH + du);
    *(ui4*)(hs + ((size_t)(dir*512 + tp)*64 + bg*16 + db)*256 + du) = hv;
  }
}

// ---------------- K4: emissions[b][s][17] = [h_f, h_b] @ cls_w^T + cls_b (fp32) ----------------
__global__ __launch_bounds__(256) void k_emis(
    const ushort_t* __restrict__ hs, const float* __restrict__ clsw,
    const float* __restrict__ clsb, float* __restrict__ emis)
{
  int tid = threadIdx.x;
  if (tid >= 255) return;
  int wi = blockIdx.x * 15 + tid / 17;
  int tau = tid % 17;
  if (wi >= B_ * S_) return;
  int b = wi >> 9, s = wi & 511;
  const ushort_t* hf  = hs + ((size_t)s*64 + b) * 256;
  const ushort_t* hbk = hs + (((size_t)512 + s)*64 + b) * 256;
  const float* cwf = clsw + (size_t)tau * 512;
  const float* cwb = cwf + 256;
  union { unsigned int u; float f; } bc;
  float acc = clsb[tau];
  #pragma unroll 4
  for (int k = 0; k < 256; k += 8) {
    ui4 h8 = *(const ui4*)(hf + k);
    f4 wa = *(const f4*)(cwf + k); f4 wb = *(const f4*)(cwf + k + 4);
    bc.u = h8[0] << 16;           acc += bc.f * wa[0];
    bc.u = h8[0] & 0xffff0000u;   acc += bc.f * wa[1];
    bc.u = h8[1] << 16;           acc += bc.f * wa[2];
    bc.u = h8[1] & 0xffff0000u;   acc += bc.f * wa[3];
    bc.u = h8[2] << 16;           acc += bc.f * wb[0];
    bc.u = h8[2] & 0xffff0000u;   acc += bc.f * wb[1];
    bc.u = h8[3] << 16;           acc += bc.f * wb[2];
    bc.u = h8[3] & 0xffff0000u;   acc += bc.f * wb[3];
  }
  #pragma unroll 4
  for (int k = 0; k < 256; k += 8) {
    ui4 h8 = *(const ui4*)(hbk + k);
    f4 wa = *(const f4*)(cwb + k); f4 wb = *(const f4*)(cwb + k + 4);
    bc.u = h8[0] << 16;           acc += bc.f * wa[0];
    bc.u = h8[0] & 0xffff0000u;   acc += bc.f * wa[1];
    bc.u = h8[1] << 16;           acc += bc.f * wa[2];
    bc.u = h8[1] & 0xffff0000u;   acc += bc.f * wa[3];
    bc.u = h8[2] << 16;           acc += bc.f * wb[0];
    bc.u = h8[2] & 0xffff0000u;   acc += bc.f * wb[1];
    bc.u = h8[3] << 16;           acc += bc.f * wb[2];
    bc.u = h8[3] & 0xffff0000u;   acc += bc.f * wb[3];
  }
  emis[(size_t)wi * 17 + tau] = acc;
}

// ---------------- K5: CRF — 64 blocks (one per batch): wave0 = loss fwd, wave1 = viterbi --------
__global__ __launch_bounds__(128) void k_crf(
    const float* __restrict__ emis, const int* __restrict__ labels,
    const int* __restrict__ mask, const float* __restrict__ startt,
    const float* __restrict__ endt, const float* __restrict__ trans,
    float* __restrict__ lossp, float* __restrict__ outp)
{
  __shared__ unsigned char bps[511][17];
  int b = blockIdx.x;
  int tid = threadIdx.x, wv = tid >> 6, l = tid & 63;
  int tauc = (l < 17) ? l : 0;
  float tc[17];
  #pragma unroll
  for (int i = 0; i < 17; i++) tc[i] = trans[i*17 + tauc];
  const float* eb = emis + (size_t)b * 512 * 17;
  float alpha = startt[tauc] + eb[tauc];
  if (l >= 17) alpha = -3e30f;

  if (wv == 0) {
    float e_cur = (l < 17) ? eb[17 + l] : 0.f;
    int   m_cur = mask[b*512 + 1];
    for (int t = 1; t < 512; t++) {
      float e_nxt = 0.f; int m_nxt = 1;
      if (t < 511) {
        e_nxt = (l < 17) ? eb[(t+1)*17 + l] : 0.f;
        m_nxt = mask[b*512 + t + 1];
      }
      float arr[17];
      #pragma unroll
      for (int i = 0; i < 17; i++) arr[i] = __shfl(alpha, i) + tc[i];
      // depth-5 fmax tree
      float t8[8];
      #pragma unroll
      for (int i = 0; i < 8; i++) t8[i] = fmaxf(arr[2*i], arr[2*i+1]);
      float t4a = fmaxf(t8[0], t8[1]), t4b = fmaxf(t8[2], t8[3]);
      float t4c = fmaxf(t8[4], t8[5]), t4d = fmaxf(t8[6], t8[7]);
      float mx = fmaxf(fmaxf(fmaxf(t4a, t4b), fmaxf(t4c, t4d)), arr[16]);
      // exp + depth-5 add tree
      float ex[17];
      #pragma unroll
      for (int i = 0; i < 17; i++) ex[i] = __expf(arr[i] - mx);
      float s8[8];
      #pragma unroll
      for (int i = 0; i < 8; i++) s8[i] = ex[2*i] + ex[2*i+1];
      float ss = (((s8[0] + s8[1]) + (s8[2] + s8[3]))
               + ((s8[4] + s8[5]) + (s8[6] + s8[7]))) + ex[16];
      float nxt = mx + __logf(ss) + e_cur;
      if (m_cur > 0 && l < 17) alpha = nxt;
      e_cur = e_nxt; m_cur = m_nxt;
    }
    float a2 = (l < 17) ? (alpha + endt[l]) : -3e30f;
    float mx = a2;
    #pragma unroll
    for (int o = 32; o > 0; o >>= 1) mx = fmaxf(mx, __shfl_xor(mx, o));
    float ss = (l < 17) ? __expf(a2 - mx) : 0.f;
    #pragma unroll
    for (int o = 32; o > 0; o >>= 1) ss += __shfl_xor(ss, o);
    float denom = mx + __logf(ss);
    float ns = 0.f; int msum = 0;
    for (int t = l; t < 512; t += 64) {
      int tg = labels[b*512 + t];
      int mt = mask[b*512 + t];
      msum += (mt > 0);
      if (mt > 0) {
        ns += eb[t*17 + tg];
        if (t > 0) ns += trans[labels[b*512 + t - 1]*17 + tg];
      }
    }
    #pragma unroll
    for (int o = 32; o > 0; o >>= 1) { ns += __shfl_xor(ns, o); msum += __shfl_xor(msum, o); }
    if (l == 0) {
      int lidx = msum - 1;
      float num = ns + startt[labels[b*512]] + endt[labels[b*512 + lidx]];
      lossp[b] = num - denom;
    }
  } else {
    float e_cur = (l < 17) ? eb[17 + l] : 0.f;
    int   m_cur = mask[b*512 + 1];
    for (int t = 1; t < 512; t++) {
      float e_nxt = 0.f; int m_nxt = 1;
      if (t < 511) {
        e_nxt = (l < 17) ? eb[(t+1)*17 + l] : 0.f;
        m_nxt = mask[b*512 + t + 1];
      }
      float av[17];
      #pragma unroll
      for (int i = 0; i < 17; i++) av[i] = __shfl(alpha, i) + tc[i];
      // depth-5 argmax tournament, left-priority (>=): first-max == np.argmax
      float v8l[8]; int i8[8];
      #pragma unroll
      for (int i = 0; i < 8; i++) {
        int take = (av[2*i] >= av[2*i+1]);
        v8l[i] = take ? av[2*i] : av[2*i+1];
        i8[i]  = take ? 2*i : 2*i+1;
      }
      float v4l[4]; int i4[4];
      #pragma unroll
      for (int i = 0; i < 4; i++) {
        int take = (v8l[2*i] >= v8l[2*i+1]);
        v4l[i] = take ? v8l[2*i] : v8l[2*i+1];
        i4[i]  = take ? i8[2*i] : i8[2*i+1];
      }
      float v2a = (v4l[0] >= v4l[1]) ? v4l[0] : v4l[1];
      int   i2a = (v4l[0] >= v4l[1]) ? i4[0] : i4[1];
      float v2b = (v4l[2] >= v4l[3]) ? v4l[2] : v4l[3];
      int   i2b = (v4l[2] >= v4l[3]) ? i4[2] : i4[3];
      float v1 = (v2a >= v2b) ? v2a : v2b;
      int   i1 = (v2a >= v2b) ? i2a : i2b;
      float best = (v1 >= av[16]) ? v1 : av[16];
      int   bi   = (v1 >= av[16]) ? i1 : 16;
      float nxt = best + e_cur;
      int bpv = (m_cur > 0) ? bi : l;
      if (l < 17) {
        bps[t-1][l] = (unsigned char)bpv;
        if (m_cur > 0) alpha = nxt;
      }
      e_cur = e_nxt; m_cur = m_nxt;
    }
    float a2 = (l < 17) ? (alpha + endt[l]) : -3e30f;
    float av[17];
    #pragma unroll
    for (int i = 0; i < 17; i++) av[i] = __shfl(a2, i);
    int bt = 0; float bv2 = av[0];
    #pragma unroll
    for (int i = 1; i < 17; i++) if (av[i] > bv2) { bv2 = av[i]; bt = i; }
    if (l == 0) outp[1 + b*512 + 511] = (float)bt;
    int tg = bt;
    for (int t = 510; t >= 0; --t) {
      tg = bps[t][tg];
      if (l == 0) outp[1 + b*512 + t] = (float)tg;
    }
  }
}

// ---------------- K6: loss = -mean(num - denom), fp32 ----------------
__global__ __launch_bounds__(64) void k_final(const float* __restrict__ lossp,
                                              float* __restrict__ outp)
{
  int l = threadIdx.x;
  float v = lossp[l];
  #pragma unroll
  for (int o = 32; o > 0; o >>= 1) v += __shfl_xor(v, o);
  if (l == 0) outp[0] = -(v / 64.f);
}

// ---------------- host ----------------
extern "C" void kernel_launch(void* const* d_in, const int* in_sizes, int n_in,
                              void* d_out, int out_size, void* d_ws, size_t ws_size,
                              hipStream_t stream)
{
  (void)in_sizes; (void)n_in; (void)out_size; (void)ws_size;
  const int*   tok   = (const int*)d_in[0];
  const int*   ctok  = (const int*)d_in[1];
  const int*   labels= (const int*)d_in[2];
  const int*   amask = (const int*)d_in[3];
  const float* wemb  = (const float*)d_in[4];
  const float* cemb  = (const float*)d_in[5];
  const float* convw = (const float*)d_in[6];
  const float* convb = (const float*)d_in[7];
  const float* wihf  = (const float*)d_in[8];
  const float* whhf  = (const float*)d_in[9];
  const float* bfv   = (const float*)d_in[10];
  const float* wihb  = (const float*)d_in[11];
  const float* whhb  = (const float*)d_in[12];
  const float* bbv   = (const float*)d_in[13];
  const float* clsw  = (const float*)d_in[14];
  const float* clsb  = (const float*)d_in[15];
  const float* stt   = (const float*)d_in[16];
  const float* ent   = (const float*)d_in[17];
  const float* trn   = (const float*)d_in[18];

  // workspace layout (bytes): [z 20,971,520][gx2 134,217,728][hs 33,554,432]
  //                           [emis 2,228,224][lossp 256]
  // W_ih bf16 (1.3 MB) aliases the START of the hs region: written by k_wcvt and read by
  // k_gemm_gx, both of which complete (stream-ordered) before k_lstm writes hs.
  char* ws = (char*)d_ws;
  ushort_t* z    = (ushort_t*)(ws);
  ushort_t* gx2  = (ushort_t*)(ws + 20971520);
  ushort_t* hs   = (ushort_t*)(ws + 155189248);
  float*    emis = (float*)(ws + 188743680);
  float*    lossp= (float*)(ws + 190971904);
  ushort_t* wbf  = (ushort_t*)(ws + 155189248);   // aliases hs (dead until k_lstm)

  hipLaunchKernelGGL(k_wcvt,    dim3(640),         dim3(256), 0, stream,
                     wihf, wihb, wbf);
  hipLaunchKernelGGL(k_embed,   dim3(B_*S_/4),     dim3(256), 0, stream,
                     tok, ctok, wemb, cemb, convw, convb, z);
  hipLaunchKernelGGL(k_gemm_gx, dim3(256, 32),     dim3(256), 0, stream,
                     z, wbf, bfv, bbv, gx2);
  hipLaunchKernelGGL(k_lstm,    dim3(8),           dim3(512), 0, stream,
                     gx2, whhf, whhb, hs);
  hipLaunchKernelGGL(k_emis,    dim3((B_*S_ + 14)/15), dim3(256), 0, stream,
                     hs, clsw, clsb, emis);
  hipLaunchKernelGGL(k_crf,     dim3(64),          dim3(128), 0, stream,
                     emis, labels, amask, stt, ent, trn, lossp, (float*)d_out);
  hipLaunchKernelGGL(k_final,   dim3(1),           dim3(64),  0, stream,
                     lossp, (float*)d_out);
}